// Round 25
// baseline (103.411 us; speedup 1.0000x reference)
//
#include <hip/hip_runtime.h>

// CapsNet forward.
// packAll: w2 -> MFMA B-fragments + W_route -> f16 c-pairs   (R16 proven)
// conv_fused: conv1 from f16 sIn (stride-40 rows, 4 LDS reads/row) + padded
//   float4 weights; fp32 accum; -> sOut LDS -> conv2 MFMA (R16 proven) -> u.
// routing2: R24-proven (fixed-dp u_hat + fused it=0 s-accum, b in registers,
//   shfl-fused squash, stride-82 u_hat LDS).

typedef _Float16 half2_t __attribute__((ext_vector_type(2)));
typedef _Float16 f16x4 __attribute__((ext_vector_type(4)));
typedef _Float16 f16x8 __attribute__((ext_vector_type(8)));
typedef float f32x16 __attribute__((ext_vector_type(16)));

static __device__ __forceinline__ float fdot2f(half2_t a, half2_t b, float c) {
#if __has_builtin(__builtin_amdgcn_fdot2)
  return __builtin_amdgcn_fdot2(a, b, c, false);
#else
  return c + (float)a[0] * (float)b[0] + (float)a[1] * (float)b[1];
#endif
}

static __device__ __forceinline__ half2_t h2(unsigned int u) {
  return __builtin_bit_cast(half2_t, u);
}

static __device__ __forceinline__ unsigned int pkh2(float a, float b) {
  half2_t h;
  h[0] = (_Float16)a;
  h[1] = (_Float16)b;
  return __builtin_bit_cast(unsigned int, h);
}

static __device__ __forceinline__ f32x16 zero16() {
  f32x16 z = {0.f, 0.f, 0.f, 0.f, 0.f, 0.f, 0.f, 0.f,
              0.f, 0.f, 0.f, 0.f, 0.f, 0.f, 0.f, 0.f};
  return z;
}

// Fused packs. idx < 92160: W_route -> wPr f16 c-pairs.
//              idx < 41472: w2 -> wBg MFMA B-fragments.
__global__ __launch_bounds__(256) void packAll(
    const float* __restrict__ w2, const float* __restrict__ Wr,
    _Float16* __restrict__ wBg, unsigned int* __restrict__ wPr) {
  int idx = blockIdx.x * 256 + threadIdx.x;
  if (idx < 92160) {
    int cp = idx & 3;
    int row = idx >> 2;
    const float* src = Wr + (size_t)row * 8 + cp * 2;
    wPr[idx] = pkh2(src[0], src[1]);
  }
  if (idx < 41472) {
    int j = idx & 7;
    int lane = (idx >> 3) & 63;
    int step = idx >> 9;
    int kh = step / 9, kw = step - kh * 9;
    int co = lane & 31, ci = (lane >> 5) * 8 + j;
    wBg[idx] = (_Float16)w2[(co * 16 + ci) * 81 + kh * 9 + kw];
  }
}

// conv_fused: block = 1 sample, 320 threads (5 waves).
// conv1: f16 sIn rows (stride 40), fp32 accumulate, padded float4 weights.
__global__ __launch_bounds__(320) void conv_fused(
    const float* __restrict__ in, const float* __restrict__ w,
    const float* __restrict__ bias1, const _Float16* __restrict__ wBg,
    const float* __restrict__ bias2, float* __restrict__ u) {
  __shared__ __align__(16) _Float16 sIn16[1120]; // [28][40] f16 (28 used/row)
  __shared__ __align__(16) float sW[1728];       // [co][kh][12] f32 (9 used)
  __shared__ __align__(16) _Float16 sOut[8000];  // [ih*20+iw][20] (16 used)
  int b = blockIdx.x, t = threadIdx.x;
  const float* inb = in + b * 784;
  for (int i = t; i < 784; i += 320) {
    int r = i / 28, c = i - r * 28;
    sIn16[r * 40 + c] = (_Float16)inb[i];
  }
  for (int i = t; i < 1728; i += 320) {
    int co = i / 108, rr = i - co * 108, kh = rr / 12, kw = rr - kh * 12;
    sW[i] = (kw < 9) ? w[co * 81 + kh * 9 + kw] : 0.f;
  }
  __syncthreads();
  {
    int co = t / 20, oh = t % 20;   // 16*20 = 320 work items
    float bv = bias1[co];
    float acc[20];
#pragma unroll
    for (int j = 0; j < 20; ++j) acc[j] = bv;
#pragma unroll
    for (int kh = 0; kh < 9; ++kh) {
      const _Float16* rp = &sIn16[(oh + kh) * 40];
      f16x8 v0 = *(const f16x8*)rp;
      f16x8 v1 = *(const f16x8*)(rp + 8);
      f16x8 v2 = *(const f16x8*)(rp + 16);
      f16x4 v3 = *(const f16x4*)(rp + 24);
      float r[28];
#pragma unroll
      for (int j = 0; j < 8; ++j) r[j] = (float)v0[j];
#pragma unroll
      for (int j = 0; j < 8; ++j) r[8 + j] = (float)v1[j];
#pragma unroll
      for (int j = 0; j < 8; ++j) r[16 + j] = (float)v2[j];
#pragma unroll
      for (int j = 0; j < 4; ++j) r[24 + j] = (float)v3[j];
      const float4* wq = (const float4*)&sW[co * 108 + kh * 12];
      float4 wa = wq[0], wb = wq[1], wc = wq[2];
      float w9[9] = {wa.x, wa.y, wa.z, wa.w, wb.x, wb.y, wb.z, wb.w, wc.x};
#pragma unroll
      for (int kw = 0; kw < 9; ++kw) {
        float wv = w9[kw];
#pragma unroll
        for (int j = 0; j < 20; ++j) acc[j] += wv * r[kw + j];
      }
    }
#pragma unroll
    for (int j = 0; j < 20; ++j) sOut[(oh * 20 + j) * 20 + co] = (_Float16)acc[j];
  }
  __syncthreads();

  // ---- conv2 MFMA: waves 0-1 (rows r = wv*32 + l31; valid r < 36) ----
  int wv = t >> 6, lane = t & 63;
  if (wv < 2) {
    int l31 = lane & 31, half = lane >> 5;
    int r = wv * 32 + l31;
    int rc = (r < 36) ? r : 35;
    int oh = rc / 6, ow = rc - oh * 6;
    int tb = (oh * 40 + ow * 2) * 20 + half * 8;
    f32x16 acc = zero16();
    for (int kh = 0; kh < 9; ++kh) {
      int abase = tb + kh * 400;   // (kh*20)*20
#pragma unroll
      for (int kw = 0; kw < 9; ++kw) {
        f16x8 bf = *(const f16x8*)(wBg + ((kh * 9 + kw) * 64 + lane) * 8);
        const _Float16* ap = sOut + abase + kw * 20;
        f16x4 lo = *(const f16x4*)ap;
        f16x4 hi = *(const f16x4*)(ap + 4);
        f16x8 a = __builtin_shufflevector(lo, hi, 0, 1, 2, 3, 4, 5, 6, 7);
        acc = __builtin_amdgcn_mfma_f32_32x32x16_f16(a, bf, acc, 0, 0, 0);
      }
    }
    float bv = bias2[l31];
    int c8 = l31 >> 2;
    int ibco = (l31 & 3) * 36;
    float* ub = u + (size_t)b * 1152;
#pragma unroll
    for (int reg = 0; reg < 16; ++reg) {
      int rr = wv * 32 + (reg & 3) + 8 * (reg >> 2) + 4 * half;
      if (rr < 36) ub[(ibco + rr) * 8 + c8] = acc[reg] + bv;
    }
  }
}

// routing2: block = 2 samples, 1024 threads. Fixed-dp u_hat (960 lanes =
// 12 chunks x 80 dp, 12 i each) with fused it=0 s-accumulation; b in regs.
__global__ __launch_bounds__(1024) void routing2_kernel(
    const float* __restrict__ u, const unsigned int* __restrict__ wPr,
    float* __restrict__ out, int B) {
  __shared__ unsigned int uhh[2][11808];   // [sl][i*82+dp] f16 d-pairs (80 used)
  __shared__ unsigned int ush[2][576];     // u f16 c-pairs [i][4]
  __shared__ float cc[2][1440];
  __shared__ float spart[2][12][160];      // [sl][ch][dp*2+c]
  __shared__ float vv[2][160];
  __shared__ unsigned int vvh[2][80];
  int b0 = blockIdx.x * 2, t = threadIdx.x;
  for (int j = t; j < 1152; j += 1024) {
    int sl2 = j / 576, k = j - sl2 * 576;
    float2 p = *(const float2*)(u + (size_t)(b0 + sl2) * 1152 + k * 2);
    ush[sl2][k] = pkh2(p.x, p.y);
  }
  __syncthreads();

  // ---- u_hat: fixed dp per thread, 12 i's, 2-deep W prefetch.
  //      Also accumulates the it=0 s-partials (softmax(0) => plain sum). ----
  bool act = t < 960;
  int chf = t / 80, dpf = t - (t / 80) * 80;   // chf<12, dpf<80 when act
  if (act) {
    const uint4* W4 = (const uint4*)wPr;   // rows [i*160+o*16+d] of 8 f16
    int rowoff = (dpf >> 3) * 16 + (dpf & 7) * 2;
    int ibase = chf * 12;
    float sA0 = 0.f, sA1 = 0.f, sB0 = 0.f, sB1 = 0.f;
    uint4 w0a = W4[ibase * 160 + rowoff];
    uint4 w1a = W4[ibase * 160 + rowoff + 1];
#pragma unroll
    for (int e = 0; e < 12; ++e) {
      int i = ibase + e;
      uint4 w0b, w1b;
      if (e < 11) {
        w0b = W4[(i + 1) * 160 + rowoff];
        w1b = W4[(i + 1) * 160 + rowoff + 1];
      }
      {
        const uint2* up = (const uint2*)&ush[0][i * 4];
        uint2 ua = up[0], ub = up[1];
        half2_t u0 = h2(ua.x), u1 = h2(ua.y), u2 = h2(ub.x), u3 = h2(ub.y);
        float a0 = fdot2f(h2(w0a.x), u0,
                   fdot2f(h2(w0a.y), u1,
                   fdot2f(h2(w0a.z), u2, fdot2f(h2(w0a.w), u3, 0.f))));
        float a1 = fdot2f(h2(w1a.x), u0,
                   fdot2f(h2(w1a.y), u1,
                   fdot2f(h2(w1a.z), u2, fdot2f(h2(w1a.w), u3, 0.f))));
        uhh[0][i * 82 + dpf] = pkh2(a0, a1);
        sA0 += a0; sA1 += a1;
      }
      {
        const uint2* up = (const uint2*)&ush[1][i * 4];
        uint2 ua = up[0], ub = up[1];
        half2_t u0 = h2(ua.x), u1 = h2(ua.y), u2 = h2(ub.x), u3 = h2(ub.y);
        float a0 = fdot2f(h2(w0a.x), u0,
                   fdot2f(h2(w0a.y), u1,
                   fdot2f(h2(w0a.z), u2, fdot2f(h2(w0a.w), u3, 0.f))));
        float a1 = fdot2f(h2(w1a.x), u0,
                   fdot2f(h2(w1a.y), u1,
                   fdot2f(h2(w1a.z), u2, fdot2f(h2(w1a.w), u3, 0.f))));
        uhh[1][i * 82 + dpf] = pkh2(a0, a1);
        sB0 += a0; sB1 += a1;
      }
      w0a = w0b; w1a = w1b;
    }
    spart[0][chf][dpf * 2] = sA0;
    spart[0][chf][dpf * 2 + 1] = sA1;
    spart[1][chf][dpf * 2] = sB0;
    spart[1][chf][dpf * 2 + 1] = sB1;
  }
  __syncthreads();

  int sl = t >> 9, tl = t & 511;
  bool bown = t < 288;
  int slb = t / 144, ib = t - (t / 144) * 144;   // valid when bown
  float breg[10];
#pragma unroll
  for (int o = 0; o < 10; ++o) breg[o] = 0.f;

  for (int it = 0; it < 3; ++it) {
    if (it > 0) {
      if (bown) {   // softmax from register b -> cc
        float mx = breg[0];
#pragma unroll
        for (int o = 1; o < 10; ++o) mx = fmaxf(mx, breg[o]);
        float e[10];
        float sum = 0.f;
#pragma unroll
        for (int o = 0; o < 10; ++o) { e[o] = __expf(breg[o] - mx); sum += e[o]; }
        float inv = 1.0f / sum;
#pragma unroll
        for (int o = 0; o < 10; ++o) cc[slb][ib * 10 + o] = e[o] * inv;
      }
      __syncthreads();
      // s partials: per sample, 480 lanes = 6 i-chunks x 80 d-pairs
      if (tl < 480) {
        int ch = tl / 80, dp = tl - ch * 80;
        int o = dp >> 3;
        float a0 = 0.f, a1 = 0.f;
        int i0 = ch * 24;
        for (int i = i0; i < i0 + 24; ++i) {
          float c = cc[sl][i * 10 + o];
          half2_t h = h2(uhh[sl][i * 82 + dp]);
          a0 += c * (float)h[0]; a1 += c * (float)h[1];
        }
        spart[sl][ch][dp * 2] = a0;
        spart[sl][ch][dp * 2 + 1] = a1;
      }
      __syncthreads();
    }
    // fused s-reduce + squash: lanes tl<160 hold s[o=tl/16][d=tl%16]
    if (tl < 160) {
      float s = 0.f;
      if (it == 0) {
#pragma unroll
        for (int c = 0; c < 12; ++c) s += spart[sl][c][tl];
        s *= 0.1f;   // softmax of zeros
      } else {
#pragma unroll
        for (int c = 0; c < 6; ++c) s += spart[sl][c][tl];
      }
      float sq = s * s;
      sq += __shfl_xor(sq, 1);
      sq += __shfl_xor(sq, 2);
      sq += __shfl_xor(sq, 4);
      sq += __shfl_xor(sq, 8);
      float coef = (sq / (1.0f + sq)) / sqrtf(sq + 1e-8f);
      float v = coef * s;
      vv[sl][tl] = v;
      float vn = __shfl_xor(v, 1);
      if ((tl & 1) == 0) vvh[sl][tl >> 1] = pkh2(v, vn);
      if (it == 2 && (tl & 15) == 0)
        out[(b0 + sl) * 10 + (tl >> 4)] = coef * sqrtf(sq);   // pred = ||v||
    }
    __syncthreads();   // vvh ready
    // b-update: register accumulation on owner lanes; no barrier needed after
    if (it < 2 && bown) {
      const uint2* row = (const uint2*)&uhh[slb][ib * 82];
      const uint2* vp = (const uint2*)&vvh[slb][0];
#pragma unroll
      for (int o = 0; o < 10; ++o) {
        uint2 A0 = row[o * 4 + 0], A1 = row[o * 4 + 1];
        uint2 A2 = row[o * 4 + 2], A3 = row[o * 4 + 3];
        uint2 V0 = vp[o * 4 + 0], V1 = vp[o * 4 + 1];
        uint2 V2 = vp[o * 4 + 2], V3 = vp[o * 4 + 3];
        float da = fdot2f(h2(A0.x), h2(V0.x), fdot2f(h2(A0.y), h2(V0.y), 0.f));
        float db = fdot2f(h2(A1.x), h2(V1.x), fdot2f(h2(A1.y), h2(V1.y), 0.f));
        da = fdot2f(h2(A2.x), h2(V2.x), fdot2f(h2(A2.y), h2(V2.y), da));
        db = fdot2f(h2(A3.x), h2(V3.x), fdot2f(h2(A3.y), h2(V3.y), db));
        breg[o] += da + db;
      }
    }
  }
  if (tl < 160) out[B * 10 + (b0 + sl) * 160 + tl] = vv[sl][tl];
}

extern "C" void kernel_launch(void* const* d_in, const int* in_sizes, int n_in,
                              void* d_out, int out_size, void* d_ws, size_t ws_size,
                              hipStream_t stream) {
  const float* in = (const float*)d_in[0];
  const float* w1 = (const float*)d_in[1];
  const float* b1 = (const float*)d_in[2];
  const float* w2 = (const float*)d_in[3];
  const float* b2 = (const float*)d_in[4];
  const float* Wr = (const float*)d_in[5];
  float* out = (float*)d_out;
  int B = in_sizes[0] / 784;
  float* wsf = (float*)d_ws;

  float* u = wsf;                                    // [B][1152] f32
  float* tail = wsf + (size_t)B * 1152;
  _Float16* wBg = (_Float16*)tail;                   // 41472 f16 = 20736 f
  unsigned int* wPr = (unsigned int*)(tail + 20736); // 92160 dw

  packAll<<<360, 256, 0, stream>>>(w2, Wr, wBg, wPr);
  conv_fused<<<B, 320, 0, stream>>>(in, w1, b1, wBg, b2, u);
  routing2_kernel<<<B / 2, 1024, 0, stream>>>(u, wPr, out, B);
}

// Round 26
// 92.309 us; speedup vs baseline: 1.1203x; 1.1203x over previous
//
#include <hip/hip_runtime.h>

// CapsNet forward.
// packAll: w2 -> MFMA B-fragments + W_route -> f16 c-pairs   (R16 proven)
// conv_fused: R24-proven fp32 conv1 with ONE change: thread map oh=t>>4,
//   co=t&15 (was co=t/20,oh=t%20) -> sOut store conflicts ~10-way -> 2-way.
//   conv2 MFMA unchanged. Bitwise-identical outputs.
// routing2: R24-proven (fixed-dp u_hat + fused it=0 s-accum, b in registers,
//   shfl-fused squash, stride-82 u_hat LDS).

typedef _Float16 half2_t __attribute__((ext_vector_type(2)));
typedef _Float16 f16x4 __attribute__((ext_vector_type(4)));
typedef _Float16 f16x8 __attribute__((ext_vector_type(8)));
typedef float f32x16 __attribute__((ext_vector_type(16)));

static __device__ __forceinline__ float fdot2f(half2_t a, half2_t b, float c) {
#if __has_builtin(__builtin_amdgcn_fdot2)
  return __builtin_amdgcn_fdot2(a, b, c, false);
#else
  return c + (float)a[0] * (float)b[0] + (float)a[1] * (float)b[1];
#endif
}

static __device__ __forceinline__ half2_t h2(unsigned int u) {
  return __builtin_bit_cast(half2_t, u);
}

static __device__ __forceinline__ unsigned int pkh2(float a, float b) {
  half2_t h;
  h[0] = (_Float16)a;
  h[1] = (_Float16)b;
  return __builtin_bit_cast(unsigned int, h);
}

static __device__ __forceinline__ f32x16 zero16() {
  f32x16 z = {0.f, 0.f, 0.f, 0.f, 0.f, 0.f, 0.f, 0.f,
              0.f, 0.f, 0.f, 0.f, 0.f, 0.f, 0.f, 0.f};
  return z;
}

// Fused packs. idx < 92160: W_route -> wPr f16 c-pairs.
//              idx < 41472: w2 -> wBg MFMA B-fragments.
__global__ __launch_bounds__(256) void packAll(
    const float* __restrict__ w2, const float* __restrict__ Wr,
    _Float16* __restrict__ wBg, unsigned int* __restrict__ wPr) {
  int idx = blockIdx.x * 256 + threadIdx.x;
  if (idx < 92160) {
    int cp = idx & 3;
    int row = idx >> 2;
    const float* src = Wr + (size_t)row * 8 + cp * 2;
    wPr[idx] = pkh2(src[0], src[1]);
  }
  if (idx < 41472) {
    int j = idx & 7;
    int lane = (idx >> 3) & 63;
    int step = idx >> 9;
    int kh = step / 9, kw = step - kh * 9;
    int co = lane & 31, ci = (lane >> 5) * 8 + j;
    wBg[idx] = (_Float16)w2[(co * 16 + ci) * 81 + kh * 9 + kw];
  }
}

// conv_fused: block = 1 sample, 320 threads (5 waves).
__global__ __launch_bounds__(320) void conv_fused(
    const float* __restrict__ in, const float* __restrict__ w,
    const float* __restrict__ bias1, const _Float16* __restrict__ wBg,
    const float* __restrict__ bias2, float* __restrict__ u) {
  __shared__ __align__(16) float sIn[784];      // 28x28
  __shared__ float sW[1296];                    // 16x81
  __shared__ __align__(16) _Float16 sOut[8000]; // [ih*20+iw][20] (16 used)
  int b = blockIdx.x, t = threadIdx.x;
  const float* inb = in + b * 784;
  for (int i = t; i < 784; i += 320) sIn[i] = inb[i];
  for (int i = t; i < 1296; i += 320) sW[i] = w[i];
  __syncthreads();
  {
    // thread map: wave spans 4 oh x 16 co -> sOut store conflicts 2-way
    int oh = t >> 4, co = t & 15;   // 20*16 = 320 work items
    float bv = bias1[co];
    float acc[20];
#pragma unroll
    for (int j = 0; j < 20; ++j) acc[j] = bv;
#pragma unroll
    for (int kh = 0; kh < 9; ++kh) {
      float r[28];
      const float4* row = (const float4*)&sIn[(oh + kh) * 28];
#pragma unroll
      for (int q = 0; q < 7; ++q) {
        float4 v = row[q];
        r[q * 4 + 0] = v.x; r[q * 4 + 1] = v.y; r[q * 4 + 2] = v.z; r[q * 4 + 3] = v.w;
      }
      const float* wr = &sW[co * 81 + kh * 9];
#pragma unroll
      for (int kw = 0; kw < 9; ++kw) {
        float wv = wr[kw];
#pragma unroll
        for (int j = 0; j < 20; ++j) acc[j] += wv * r[kw + j];
      }
    }
#pragma unroll
    for (int j = 0; j < 20; ++j) sOut[(oh * 20 + j) * 20 + co] = (_Float16)acc[j];
  }
  __syncthreads();

  // ---- conv2 MFMA: waves 0-1 (rows r = wv*32 + l31; valid r < 36) ----
  int wv = t >> 6, lane = t & 63;
  if (wv < 2) {
    int l31 = lane & 31, half = lane >> 5;
    int r = wv * 32 + l31;
    int rc = (r < 36) ? r : 35;
    int oh = rc / 6, ow = rc - oh * 6;
    int tb = (oh * 40 + ow * 2) * 20 + half * 8;
    f32x16 acc = zero16();
    for (int kh = 0; kh < 9; ++kh) {
      int abase = tb + kh * 400;   // (kh*20)*20
#pragma unroll
      for (int kw = 0; kw < 9; ++kw) {
        f16x8 bf = *(const f16x8*)(wBg + ((kh * 9 + kw) * 64 + lane) * 8);
        const _Float16* ap = sOut + abase + kw * 20;
        f16x4 lo = *(const f16x4*)ap;
        f16x4 hi = *(const f16x4*)(ap + 4);
        f16x8 a = __builtin_shufflevector(lo, hi, 0, 1, 2, 3, 4, 5, 6, 7);
        acc = __builtin_amdgcn_mfma_f32_32x32x16_f16(a, bf, acc, 0, 0, 0);
      }
    }
    float bv = bias2[l31];
    int c8 = l31 >> 2;
    int ibco = (l31 & 3) * 36;
    float* ub = u + (size_t)b * 1152;
#pragma unroll
    for (int reg = 0; reg < 16; ++reg) {
      int rr = wv * 32 + (reg & 3) + 8 * (reg >> 2) + 4 * half;
      if (rr < 36) ub[(ibco + rr) * 8 + c8] = acc[reg] + bv;
    }
  }
}

// routing2: block = 2 samples, 1024 threads. Fixed-dp u_hat (960 lanes =
// 12 chunks x 80 dp, 12 i each) with fused it=0 s-accumulation; b in regs.
__global__ __launch_bounds__(1024) void routing2_kernel(
    const float* __restrict__ u, const unsigned int* __restrict__ wPr,
    float* __restrict__ out, int B) {
  __shared__ unsigned int uhh[2][11808];   // [sl][i*82+dp] f16 d-pairs (80 used)
  __shared__ unsigned int ush[2][576];     // u f16 c-pairs [i][4]
  __shared__ float cc[2][1440];
  __shared__ float spart[2][12][160];      // [sl][ch][dp*2+c]
  __shared__ float vv[2][160];
  __shared__ unsigned int vvh[2][80];
  int b0 = blockIdx.x * 2, t = threadIdx.x;
  for (int j = t; j < 1152; j += 1024) {
    int sl2 = j / 576, k = j - sl2 * 576;
    float2 p = *(const float2*)(u + (size_t)(b0 + sl2) * 1152 + k * 2);
    ush[sl2][k] = pkh2(p.x, p.y);
  }
  __syncthreads();

  // ---- u_hat: fixed dp per thread, 12 i's, 2-deep W prefetch.
  //      Also accumulates the it=0 s-partials (softmax(0) => plain sum). ----
  bool act = t < 960;
  int chf = t / 80, dpf = t - (t / 80) * 80;   // chf<12, dpf<80 when act
  if (act) {
    const uint4* W4 = (const uint4*)wPr;   // rows [i*160+o*16+d] of 8 f16
    int rowoff = (dpf >> 3) * 16 + (dpf & 7) * 2;
    int ibase = chf * 12;
    float sA0 = 0.f, sA1 = 0.f, sB0 = 0.f, sB1 = 0.f;
    uint4 w0a = W4[ibase * 160 + rowoff];
    uint4 w1a = W4[ibase * 160 + rowoff + 1];
#pragma unroll
    for (int e = 0; e < 12; ++e) {
      int i = ibase + e;
      uint4 w0b, w1b;
      if (e < 11) {
        w0b = W4[(i + 1) * 160 + rowoff];
        w1b = W4[(i + 1) * 160 + rowoff + 1];
      }
      {
        const uint2* up = (const uint2*)&ush[0][i * 4];
        uint2 ua = up[0], ub = up[1];
        half2_t u0 = h2(ua.x), u1 = h2(ua.y), u2 = h2(ub.x), u3 = h2(ub.y);
        float a0 = fdot2f(h2(w0a.x), u0,
                   fdot2f(h2(w0a.y), u1,
                   fdot2f(h2(w0a.z), u2, fdot2f(h2(w0a.w), u3, 0.f))));
        float a1 = fdot2f(h2(w1a.x), u0,
                   fdot2f(h2(w1a.y), u1,
                   fdot2f(h2(w1a.z), u2, fdot2f(h2(w1a.w), u3, 0.f))));
        uhh[0][i * 82 + dpf] = pkh2(a0, a1);
        sA0 += a0; sA1 += a1;
      }
      {
        const uint2* up = (const uint2*)&ush[1][i * 4];
        uint2 ua = up[0], ub = up[1];
        half2_t u0 = h2(ua.x), u1 = h2(ua.y), u2 = h2(ub.x), u3 = h2(ub.y);
        float a0 = fdot2f(h2(w0a.x), u0,
                   fdot2f(h2(w0a.y), u1,
                   fdot2f(h2(w0a.z), u2, fdot2f(h2(w0a.w), u3, 0.f))));
        float a1 = fdot2f(h2(w1a.x), u0,
                   fdot2f(h2(w1a.y), u1,
                   fdot2f(h2(w1a.z), u2, fdot2f(h2(w1a.w), u3, 0.f))));
        uhh[1][i * 82 + dpf] = pkh2(a0, a1);
        sB0 += a0; sB1 += a1;
      }
      w0a = w0b; w1a = w1b;
    }
    spart[0][chf][dpf * 2] = sA0;
    spart[0][chf][dpf * 2 + 1] = sA1;
    spart[1][chf][dpf * 2] = sB0;
    spart[1][chf][dpf * 2 + 1] = sB1;
  }
  __syncthreads();

  int sl = t >> 9, tl = t & 511;
  bool bown = t < 288;
  int slb = t / 144, ib = t - (t / 144) * 144;   // valid when bown
  float breg[10];
#pragma unroll
  for (int o = 0; o < 10; ++o) breg[o] = 0.f;

  for (int it = 0; it < 3; ++it) {
    if (it > 0) {
      if (bown) {   // softmax from register b -> cc
        float mx = breg[0];
#pragma unroll
        for (int o = 1; o < 10; ++o) mx = fmaxf(mx, breg[o]);
        float e[10];
        float sum = 0.f;
#pragma unroll
        for (int o = 0; o < 10; ++o) { e[o] = __expf(breg[o] - mx); sum += e[o]; }
        float inv = 1.0f / sum;
#pragma unroll
        for (int o = 0; o < 10; ++o) cc[slb][ib * 10 + o] = e[o] * inv;
      }
      __syncthreads();
      // s partials: per sample, 480 lanes = 6 i-chunks x 80 d-pairs
      if (tl < 480) {
        int ch = tl / 80, dp = tl - ch * 80;
        int o = dp >> 3;
        float a0 = 0.f, a1 = 0.f;
        int i0 = ch * 24;
        for (int i = i0; i < i0 + 24; ++i) {
          float c = cc[sl][i * 10 + o];
          half2_t h = h2(uhh[sl][i * 82 + dp]);
          a0 += c * (float)h[0]; a1 += c * (float)h[1];
        }
        spart[sl][ch][dp * 2] = a0;
        spart[sl][ch][dp * 2 + 1] = a1;
      }
      __syncthreads();
    }
    // fused s-reduce + squash: lanes tl<160 hold s[o=tl/16][d=tl%16]
    if (tl < 160) {
      float s = 0.f;
      if (it == 0) {
#pragma unroll
        for (int c = 0; c < 12; ++c) s += spart[sl][c][tl];
        s *= 0.1f;   // softmax of zeros
      } else {
#pragma unroll
        for (int c = 0; c < 6; ++c) s += spart[sl][c][tl];
      }
      float sq = s * s;
      sq += __shfl_xor(sq, 1);
      sq += __shfl_xor(sq, 2);
      sq += __shfl_xor(sq, 4);
      sq += __shfl_xor(sq, 8);
      float coef = (sq / (1.0f + sq)) / sqrtf(sq + 1e-8f);
      float v = coef * s;
      vv[sl][tl] = v;
      float vn = __shfl_xor(v, 1);
      if ((tl & 1) == 0) vvh[sl][tl >> 1] = pkh2(v, vn);
      if (it == 2 && (tl & 15) == 0)
        out[(b0 + sl) * 10 + (tl >> 4)] = coef * sqrtf(sq);   // pred = ||v||
    }
    __syncthreads();   // vvh ready
    // b-update: register accumulation on owner lanes; no barrier needed after
    if (it < 2 && bown) {
      const uint2* row = (const uint2*)&uhh[slb][ib * 82];
      const uint2* vp = (const uint2*)&vvh[slb][0];
#pragma unroll
      for (int o = 0; o < 10; ++o) {
        uint2 A0 = row[o * 4 + 0], A1 = row[o * 4 + 1];
        uint2 A2 = row[o * 4 + 2], A3 = row[o * 4 + 3];
        uint2 V0 = vp[o * 4 + 0], V1 = vp[o * 4 + 1];
        uint2 V2 = vp[o * 4 + 2], V3 = vp[o * 4 + 3];
        float da = fdot2f(h2(A0.x), h2(V0.x), fdot2f(h2(A0.y), h2(V0.y), 0.f));
        float db = fdot2f(h2(A1.x), h2(V1.x), fdot2f(h2(A1.y), h2(V1.y), 0.f));
        da = fdot2f(h2(A2.x), h2(V2.x), fdot2f(h2(A2.y), h2(V2.y), da));
        db = fdot2f(h2(A3.x), h2(V3.x), fdot2f(h2(A3.y), h2(V3.y), db));
        breg[o] += da + db;
      }
    }
  }
  if (tl < 160) out[B * 10 + (b0 + sl) * 160 + tl] = vv[sl][tl];
}

extern "C" void kernel_launch(void* const* d_in, const int* in_sizes, int n_in,
                              void* d_out, int out_size, void* d_ws, size_t ws_size,
                              hipStream_t stream) {
  const float* in = (const float*)d_in[0];
  const float* w1 = (const float*)d_in[1];
  const float* b1 = (const float*)d_in[2];
  const float* w2 = (const float*)d_in[3];
  const float* b2 = (const float*)d_in[4];
  const float* Wr = (const float*)d_in[5];
  float* out = (float*)d_out;
  int B = in_sizes[0] / 784;
  float* wsf = (float*)d_ws;

  float* u = wsf;                                    // [B][1152] f32
  float* tail = wsf + (size_t)B * 1152;
  _Float16* wBg = (_Float16*)tail;                   // 41472 f16 = 20736 f
  unsigned int* wPr = (unsigned int*)(tail + 20736); // 92160 dw

  packAll<<<360, 256, 0, stream>>>(w2, Wr, wBg, wPr);
  conv_fused<<<B, 320, 0, stream>>>(in, w1, b1, wBg, b2, u);
  routing2_kernel<<<B / 2, 1024, 0, stream>>>(u, wPr, out, B);
}

// Round 27
// 92.222 us; speedup vs baseline: 1.1213x; 1.0009x over previous
//
#include <hip/hip_runtime.h>

// CapsNet forward — conv+routing fused at 2 samples/block, 1024 threads.
// packAll: w2 -> MFMA B-fragments + W_route -> f16 c-pairs   (R16 proven)
// capsnet_fused:
//   phase 1: conv1 fp32 (R26 map, threads 0-639) -> sOut[2] f16 (LDS)
//   phase 2: conv2 MFMA (waves 0-3, R26 math) -> ush f16 (LDS; u never in HBM)
//   phase 3+: R24-proven routing (fixed-dp u_hat + fused it=0 s-accum,
//             b in registers, shfl-fused squash, stride-82 uhh).
//   LDS: {sIn,sW,sOut} alias the uhh region (disjoint lifetimes); ~125 KB.

typedef _Float16 half2_t __attribute__((ext_vector_type(2)));
typedef _Float16 f16x4 __attribute__((ext_vector_type(4)));
typedef _Float16 f16x8 __attribute__((ext_vector_type(8)));
typedef float f32x16 __attribute__((ext_vector_type(16)));

static __device__ __forceinline__ float fdot2f(half2_t a, half2_t b, float c) {
#if __has_builtin(__builtin_amdgcn_fdot2)
  return __builtin_amdgcn_fdot2(a, b, c, false);
#else
  return c + (float)a[0] * (float)b[0] + (float)a[1] * (float)b[1];
#endif
}

static __device__ __forceinline__ half2_t h2(unsigned int u) {
  return __builtin_bit_cast(half2_t, u);
}

static __device__ __forceinline__ unsigned int pkh2(float a, float b) {
  half2_t h;
  h[0] = (_Float16)a;
  h[1] = (_Float16)b;
  return __builtin_bit_cast(unsigned int, h);
}

static __device__ __forceinline__ f32x16 zero16() {
  f32x16 z = {0.f, 0.f, 0.f, 0.f, 0.f, 0.f, 0.f, 0.f,
              0.f, 0.f, 0.f, 0.f, 0.f, 0.f, 0.f, 0.f};
  return z;
}

// Fused packs. idx < 92160: W_route -> wPr f16 c-pairs.
//              idx < 41472: w2 -> wBg MFMA B-fragments.
__global__ __launch_bounds__(256) void packAll(
    const float* __restrict__ w2, const float* __restrict__ Wr,
    _Float16* __restrict__ wBg, unsigned int* __restrict__ wPr) {
  int idx = blockIdx.x * 256 + threadIdx.x;
  if (idx < 92160) {
    int cp = idx & 3;
    int row = idx >> 2;
    const float* src = Wr + (size_t)row * 8 + cp * 2;
    wPr[idx] = pkh2(src[0], src[1]);
  }
  if (idx < 41472) {
    int j = idx & 7;
    int lane = (idx >> 3) & 63;
    int step = idx >> 9;
    int kh = step / 9, kw = step - kh * 9;
    int co = lane & 31, ci = (lane >> 5) * 8 + j;
    wBg[idx] = (_Float16)w2[(co * 16 + ci) * 81 + kh * 9 + kw];
  }
}

// capsnet_fused: 2 samples/block, 1024 threads.
__global__ __launch_bounds__(1024) void capsnet_fused(
    const float* __restrict__ in, const float* __restrict__ w1g,
    const float* __restrict__ bias1, const _Float16* __restrict__ wBg,
    const float* __restrict__ bias2, const unsigned int* __restrict__ wPr,
    float* __restrict__ out, int B) {
  // uhh region doubles as conv scratch (disjoint lifetimes):
  //   conv view:  sIn [2][784] f32 @0 | sW [1296] f32 @6272B | sOut [2][8000] f16 @11456B
  //   routing view: uhh [2][11808] u32 @0   (94464 B)
  __shared__ __align__(16) unsigned char smemA[94464];
  __shared__ unsigned int ush[2][576];     // u f16 c-pairs [i][4]  (persistent)
  __shared__ float cc[2][1440];
  __shared__ float spart[2][12][160];
  __shared__ float vv[2][160];
  __shared__ unsigned int vvh[2][80];
  float* sIn = (float*)smemA;                         // [2][784]
  float* sW = (float*)(smemA + 6272);                 // [1296]
  _Float16* sOut = (_Float16*)(smemA + 11456);        // [2][8000]
  unsigned int* uhh0 = (unsigned int*)smemA;          // [11808]
  unsigned int* uhh1 = (unsigned int*)(smemA + 47232);// [11808]

  int b0 = blockIdx.x * 2, t = threadIdx.x;
  for (int j = t; j < 1568; j += 1024) {
    int s = j / 784, k = j - s * 784;
    sIn[j] = in[(size_t)(b0 + s) * 784 + k];
  }
  for (int j = t; j < 1296; j += 1024) sW[j] = w1g[j];
  __syncthreads();

  // ---- conv1 (R26 map): threads 0-639, waves 0-4 = s0, 5-9 = s1 ----
  if (t < 640) {
    int s = (t >= 320) ? 1 : 0;
    int tt = t - s * 320;
    int oh = tt >> 4, co = tt & 15;   // wave spans 4 oh x 16 co
    float bv = bias1[co];
    float acc[20];
#pragma unroll
    for (int j = 0; j < 20; ++j) acc[j] = bv;
#pragma unroll
    for (int kh = 0; kh < 9; ++kh) {
      float r[28];
      const float4* row = (const float4*)&sIn[s * 784 + (oh + kh) * 28];
#pragma unroll
      for (int q = 0; q < 7; ++q) {
        float4 v = row[q];
        r[q * 4 + 0] = v.x; r[q * 4 + 1] = v.y;
        r[q * 4 + 2] = v.z; r[q * 4 + 3] = v.w;
      }
      const float* wr = &sW[co * 81 + kh * 9];
#pragma unroll
      for (int kw = 0; kw < 9; ++kw) {
        float wv = wr[kw];
#pragma unroll
        for (int j = 0; j < 20; ++j) acc[j] += wv * r[kw + j];
      }
    }
#pragma unroll
    for (int j = 0; j < 20; ++j)
      sOut[s * 8000 + (oh * 20 + j) * 20 + co] = (_Float16)acc[j];
  }
  __syncthreads();

  // ---- conv2 MFMA: waves 0-3 (wave = s*2 + tile); writes ush f16 ----
  int wvv = t >> 6, lane = t & 63;
  if (wvv < 4) {
    int s = wvv >> 1, tile = wvv & 1;
    int l31 = lane & 31, half = lane >> 5;
    int r = tile * 32 + l31;
    int rc = (r < 36) ? r : 35;
    int oh = rc / 6, ow = rc - oh * 6;
    int tb = s * 8000 + (oh * 40 + ow * 2) * 20 + half * 8;
    f32x16 acc = zero16();
    for (int kh = 0; kh < 9; ++kh) {
      int abase = tb + kh * 400;
#pragma unroll
      for (int kw = 0; kw < 9; ++kw) {
        f16x8 bf = *(const f16x8*)(wBg + ((kh * 9 + kw) * 64 + lane) * 8);
        const _Float16* ap = sOut + abase + kw * 20;
        f16x4 lo = *(const f16x4*)ap;
        f16x4 hi = *(const f16x4*)(ap + 4);
        f16x8 a = __builtin_shufflevector(lo, hi, 0, 1, 2, 3, 4, 5, 6, 7);
        acc = __builtin_amdgcn_mfma_f32_32x32x16_f16(a, bf, acc, 0, 0, 0);
      }
    }
    float bv = bias2[l31];
    int c8 = l31 >> 2;
    int ibco = (l31 & 3) * 36;
    _Float16* ushf = (_Float16*)&ush[s][0];
#pragma unroll
    for (int reg = 0; reg < 16; ++reg) {
      int rr = tile * 32 + (reg & 3) + 8 * (reg >> 2) + 4 * half;
      if (rr < 36) ushf[(ibco + rr) * 8 + c8] = (_Float16)(acc[reg] + bv);
    }
  }
  __syncthreads();   // sOut dead; ush ready; uhh region free

  // ---- u_hat: fixed dp per thread, 12 i's, 2-deep W prefetch.
  //      Also accumulates the it=0 s-partials. (R24 proven) ----
  bool act = t < 960;
  int chf = t / 80, dpf = t - (t / 80) * 80;
  if (act) {
    const uint4* W4 = (const uint4*)wPr;   // rows [i*160+o*16+d] of 8 f16
    int rowoff = (dpf >> 3) * 16 + (dpf & 7) * 2;
    int ibase = chf * 12;
    float sA0 = 0.f, sA1 = 0.f, sB0 = 0.f, sB1 = 0.f;
    uint4 w0a = W4[ibase * 160 + rowoff];
    uint4 w1a = W4[ibase * 160 + rowoff + 1];
#pragma unroll
    for (int e = 0; e < 12; ++e) {
      int i = ibase + e;
      uint4 w0b, w1b;
      if (e < 11) {
        w0b = W4[(i + 1) * 160 + rowoff];
        w1b = W4[(i + 1) * 160 + rowoff + 1];
      }
      {
        const uint2* up = (const uint2*)&ush[0][i * 4];
        uint2 ua = up[0], ub = up[1];
        half2_t u0 = h2(ua.x), u1 = h2(ua.y), u2 = h2(ub.x), u3 = h2(ub.y);
        float a0 = fdot2f(h2(w0a.x), u0,
                   fdot2f(h2(w0a.y), u1,
                   fdot2f(h2(w0a.z), u2, fdot2f(h2(w0a.w), u3, 0.f))));
        float a1 = fdot2f(h2(w1a.x), u0,
                   fdot2f(h2(w1a.y), u1,
                   fdot2f(h2(w1a.z), u2, fdot2f(h2(w1a.w), u3, 0.f))));
        uhh0[i * 82 + dpf] = pkh2(a0, a1);
        sA0 += a0; sA1 += a1;
      }
      {
        const uint2* up = (const uint2*)&ush[1][i * 4];
        uint2 ua = up[0], ub = up[1];
        half2_t u0 = h2(ua.x), u1 = h2(ua.y), u2 = h2(ub.x), u3 = h2(ub.y);
        float a0 = fdot2f(h2(w0a.x), u0,
                   fdot2f(h2(w0a.y), u1,
                   fdot2f(h2(w0a.z), u2, fdot2f(h2(w0a.w), u3, 0.f))));
        float a1 = fdot2f(h2(w1a.x), u0,
                   fdot2f(h2(w1a.y), u1,
                   fdot2f(h2(w1a.z), u2, fdot2f(h2(w1a.w), u3, 0.f))));
        uhh1[i * 82 + dpf] = pkh2(a0, a1);
        sB0 += a0; sB1 += a1;
      }
      w0a = w0b; w1a = w1b;
    }
    spart[0][chf][dpf * 2] = sA0;
    spart[0][chf][dpf * 2 + 1] = sA1;
    spart[1][chf][dpf * 2] = sB0;
    spart[1][chf][dpf * 2 + 1] = sB1;
  }
  __syncthreads();

  int sl = t >> 9, tl = t & 511;
  unsigned int* uhsl = (sl == 0) ? uhh0 : uhh1;
  bool bown = t < 288;
  int slb = t / 144, ib = t - (t / 144) * 144;
  unsigned int* uhb = (slb == 0) ? uhh0 : uhh1;
  float breg[10];
#pragma unroll
  for (int o = 0; o < 10; ++o) breg[o] = 0.f;

  for (int it = 0; it < 3; ++it) {
    if (it > 0) {
      if (bown) {   // softmax from register b -> cc
        float mx = breg[0];
#pragma unroll
        for (int o = 1; o < 10; ++o) mx = fmaxf(mx, breg[o]);
        float e[10];
        float sum = 0.f;
#pragma unroll
        for (int o = 0; o < 10; ++o) { e[o] = __expf(breg[o] - mx); sum += e[o]; }
        float inv = 1.0f / sum;
#pragma unroll
        for (int o = 0; o < 10; ++o) cc[slb][ib * 10 + o] = e[o] * inv;
      }
      __syncthreads();
      // s partials: per sample, 480 lanes = 6 i-chunks x 80 d-pairs
      if (tl < 480) {
        int ch = tl / 80, dp = tl - ch * 80;
        int o = dp >> 3;
        float a0 = 0.f, a1 = 0.f;
        int i0 = ch * 24;
        for (int i = i0; i < i0 + 24; ++i) {
          float c = cc[sl][i * 10 + o];
          half2_t h = h2(uhsl[i * 82 + dp]);
          a0 += c * (float)h[0]; a1 += c * (float)h[1];
        }
        spart[sl][ch][dp * 2] = a0;
        spart[sl][ch][dp * 2 + 1] = a1;
      }
      __syncthreads();
    }
    // fused s-reduce + squash: lanes tl<160 hold s[o=tl/16][d=tl%16]
    if (tl < 160) {
      float s = 0.f;
      if (it == 0) {
#pragma unroll
        for (int c = 0; c < 12; ++c) s += spart[sl][c][tl];
        s *= 0.1f;   // softmax of zeros
      } else {
#pragma unroll
        for (int c = 0; c < 6; ++c) s += spart[sl][c][tl];
      }
      float sq = s * s;
      sq += __shfl_xor(sq, 1);
      sq += __shfl_xor(sq, 2);
      sq += __shfl_xor(sq, 4);
      sq += __shfl_xor(sq, 8);
      float coef = (sq / (1.0f + sq)) / sqrtf(sq + 1e-8f);
      float v = coef * s;
      vv[sl][tl] = v;
      float vn = __shfl_xor(v, 1);
      if ((tl & 1) == 0) vvh[sl][tl >> 1] = pkh2(v, vn);
      if (it == 2 && (tl & 15) == 0)
        out[(b0 + sl) * 10 + (tl >> 4)] = coef * sqrtf(sq);   // pred = ||v||
    }
    __syncthreads();   // vvh ready
    // b-update: register accumulation on owner lanes
    if (it < 2 && bown) {
      const uint2* row = (const uint2*)&uhb[ib * 82];
      const uint2* vp = (const uint2*)&vvh[slb][0];
#pragma unroll
      for (int o = 0; o < 10; ++o) {
        uint2 A0 = row[o * 4 + 0], A1 = row[o * 4 + 1];
        uint2 A2 = row[o * 4 + 2], A3 = row[o * 4 + 3];
        uint2 V0 = vp[o * 4 + 0], V1 = vp[o * 4 + 1];
        uint2 V2 = vp[o * 4 + 2], V3 = vp[o * 4 + 3];
        float da = fdot2f(h2(A0.x), h2(V0.x), fdot2f(h2(A0.y), h2(V0.y), 0.f));
        float db = fdot2f(h2(A1.x), h2(V1.x), fdot2f(h2(A1.y), h2(V1.y), 0.f));
        da = fdot2f(h2(A2.x), h2(V2.x), fdot2f(h2(A2.y), h2(V2.y), da));
        db = fdot2f(h2(A3.x), h2(V3.x), fdot2f(h2(A3.y), h2(V3.y), db));
        breg[o] += da + db;
      }
    }
  }
  if (tl < 160) out[B * 10 + (b0 + sl) * 160 + tl] = vv[sl][tl];
}

extern "C" void kernel_launch(void* const* d_in, const int* in_sizes, int n_in,
                              void* d_out, int out_size, void* d_ws, size_t ws_size,
                              hipStream_t stream) {
  const float* in = (const float*)d_in[0];
  const float* w1 = (const float*)d_in[1];
  const float* b1 = (const float*)d_in[2];
  const float* w2 = (const float*)d_in[3];
  const float* b2 = (const float*)d_in[4];
  const float* Wr = (const float*)d_in[5];
  float* out = (float*)d_out;
  int B = in_sizes[0] / 784;
  float* wsf = (float*)d_ws;

  _Float16* wBg = (_Float16*)wsf;                    // 41472 f16 = 20736 f
  unsigned int* wPr = (unsigned int*)(wsf + 20736);  // 92160 dw

  packAll<<<360, 256, 0, stream>>>(w2, Wr, wBg, wPr);
  capsnet_fused<<<B / 2, 1024, 0, stream>>>(in, w1, b1, wBg, b2, wPr, out, B);
}